// Round 13
// baseline (189.919 us; speedup 1.0000x reference)
//
#include <hip/hip_runtime.h>
#include <stdint.h>
#include <stddef.h>

typedef int v4i  __attribute__((ext_vector_type(4)));
typedef int v16i __attribute__((ext_vector_type(16)));

#define GLOAD16(gp, lp) __builtin_amdgcn_global_load_lds( \
    (const __attribute__((address_space(1))) void*)(gp),  \
    (__attribute__((address_space(3))) void*)(lp), 16, 0, 0)

#define PH_BAR()     __builtin_amdgcn_s_barrier()
#define WAIT_VM(n)   asm volatile("s_waitcnt vmcnt(" #n ")" ::: "memory")
#define WAIT_LGKM0() asm volatile("s_waitcnt lgkmcnt(0)" ::: "memory")
#define SCHED_FENCE() __builtin_amdgcn_sched_barrier(0)
#define PRIO1() __builtin_amdgcn_s_setprio(1)
#define PRIO0() __builtin_amdgcn_s_setprio(0)

static __device__ __forceinline__ int pack4(int a, int b, int c, int d) {
    return (a & 255) | ((b & 255) << 8) | ((c & 255) << 16) | (d << 24);
}

// ---------------- pack: int32 (values in [-128,127]) -> int8, both arrays ----------------
__global__ __launch_bounds__(256) void pack2_kernel(const int* __restrict__ srcA, v4i* __restrict__ dstA, int nA,
                                                    const int* __restrict__ srcB, v4i* __restrict__ dstB, int nB) {
    int i = blockIdx.x * blockDim.x + threadIdx.x;
    const int* src; v4i* dst;
    if (i < nA) { src = srcA; dst = dstA; }
    else { i -= nA; if (i >= nB) return; src = srcB; dst = dstB; }
    const v4i* s = reinterpret_cast<const v4i*>(src) + (size_t)i * 4;
    v4i v0 = s[0], v1 = s[1], v2 = s[2], v3 = s[3];
    v4i r;
    r.x = pack4(v0.x, v0.y, v0.z, v0.w);
    r.y = pack4(v1.x, v1.y, v1.z, v1.w);
    r.z = pack4(v2.x, v2.y, v2.z, v2.w);
    r.w = pack4(v3.x, v3.y, v3.z, v3.w);
    dst[i] = r;
}

// ====== 256x256 i8 GEMM: 32x32x32 MFMA, k-slice phases, r10 sync structure ======
// r10's schedule (A 2x32KB @0, B 3x32KB @65536 = 160KB; A(t+1)@P1, B(t+2)@P2; vm(4)
// at tile end leaves B(t+2) in flight; 1 barrier/tile) with the MFMA swapped to
// mfma_i32_32x32x32_i8 (4404 vs 3944 TOPS ubench, half the instructions). r4's 32x32
// regression was 2 acc-chains x 4 dependent MFMAs per phase; HERE each phase = one
// 32B k-slice across all 8 C-frags (4m x 2n) = 8 INDEPENDENT chains; same-acc MFMAs
// are 8 apart (~290cyc) >> dep latency. Frag reads: 6 b128/phase (af[4]+bf[2]),
// ping-pong; addressing = r4's verified colw32; C/D layout = m101's verified mapping.
__global__ __launch_bounds__(512, 1) void gemm_q8_mp(
    const char* __restrict__ Apk, const char* __restrict__ Bpk,
    const int* __restrict__ bias, const float* __restrict__ wscale,
    const float* __restrict__ is_p, const float* __restrict__ os_p,
    const int* __restrict__ zp_p,
    int* __restrict__ out, int K, int Ncols)
{
    __shared__ char lds[163840];

    const int tid  = threadIdx.x;
    const int wid  = tid >> 6;
    const int lane = tid & 63;
    const int l7 = lane & 7, l3 = lane >> 3;
    const int l31 = lane & 31, hi5 = lane >> 5;

    // bijective XCD-aware swizzle (m204)
    int swz;
    {
        const int nwg = gridDim.x;
        const int q = nwg >> 3, r = nwg & 7;
        const int xcd = blockIdx.x & 7;
        const int base = (xcd < r) ? xcd * (q + 1) : r * (q + 1) + (xcd - r) * q;
        swz = base + (blockIdx.x >> 3);
    }
    const int nbc  = Ncols >> 8;
    const int brow = swz / nbc, bcol = swz % nbc;

    const int wr = wid >> 2, wc = wid & 3;   // 2M x 4N waves, 128x64 out each

    const char* Ab = Apk + (size_t)(brow * 256 + wid * 8 + l3) * K + ((l7 ^ l3) << 4);
    const char* Bb = Bpk + (size_t)(bcol * 256 + wid * 8 + l3) * K + ((l7 ^ l3) << 4);

    // 32x32 frag reads: row = base + l31, byte col = s*32 + hi5*16; swizzle chunk^(row&7)
    int colw[4];
#pragma unroll
    for (int s = 0; s < 4; ++s) colw[s] = (((s << 1) + hi5) ^ l7) << 4;
    const int aBase = (wr << 14) + (l31 << 7);   // + Abuf + m<<12
    const int bBase = (wc << 13) + (l31 << 7);   // + 65536 + Bbuf + n<<12

    v16i acc[4][2];
#pragma unroll
    for (int m = 0; m < 4; ++m)
#pragma unroll
        for (int n = 0; n < 2; ++n)
#pragma unroll
            for (int j = 0; j < 16; ++j)
                acc[m][n][j] = 0;

    v4i afA[4], afB[4], bfA[2], bfB[2];

    auto stage = [&](const char* gb, int ldsOff, int h, int t) {
        const char* g = gb + (size_t)(h * 128) * K + ((size_t)t << 7);
        char* l = lds + (ldsOff + (h << 14) + (wid << 10));
        GLOAD16(g, l);
        GLOAD16(g + (size_t)64 * K, l + 8192);
    };
    auto ldAs = [&](v4i (&dst)[4], int bufo, int s) {
#pragma unroll
        for (int m = 0; m < 4; ++m)
            dst[m] = *(const v4i*)(lds + bufo + aBase + (m << 12) + colw[s]);
    };
    auto ldBs = [&](v4i (&dst)[2], int bufo, int s) {
#pragma unroll
        for (int n = 0; n < 2; ++n)
            dst[n] = *(const v4i*)(lds + 65536 + bufo + bBase + (n << 12) + colw[s]);
    };

    // one phase: all 8 C-frags at one k-slice; 8 independent chains
#define MQ32(afX, bfX) do {                                                       \
    _Pragma("unroll") for (int m_ = 0; m_ < 4; ++m_)                              \
    _Pragma("unroll") for (int n_ = 0; n_ < 2; ++n_)                              \
        acc[m_][n_] = __builtin_amdgcn_mfma_i32_32x32x32_i8(                      \
            afX[m_], bfX[n_], acc[m_][n_], 0, 0, 0);                              \
} while (0)

    // ---- prologue: stage A0, B0, B1; vm(4) leaves B1 in flight; preload slice0 ----
    stage(Ab, 0,             0, 0);  stage(Ab, 0,             1, 0);
    stage(Bb, 65536,         0, 0);  stage(Bb, 65536,         1, 0);
    stage(Bb, 65536 + 32768, 0, 1);  stage(Bb, 65536 + 32768, 1, 1);
    WAIT_VM(4);
    PH_BAR();
    SCHED_FENCE();
    ldAs(afA, 0, 0);
    ldBs(bfA, 0, 0);

    const int nt = K >> 7;    // K-tiles of 128 B (nt >= 3 guaranteed by dispatcher)
    int bcur = 0;             // B-buf byte offset of tile t: (t%3)*32768
    for (int t = 0; t < nt - 2; ++t) {
        const int bA  = (t & 1) << 15;
        const int nbA = (~t & 1) << 15;
        int bnx = bcur + 32768; if (bnx >= 98304) bnx -= 98304;   // (t+1)%3
        int bst = bnx  + 32768; if (bst >= 98304) bst -= 98304;   // (t+2)%3

        // P1: MFMA slice0 | read slice1 | stage A(t+1)
        ldAs(afB, bA, 1);  ldBs(bfB, bcur, 1);
        stage(Ab, nbA, 0, t + 1);  stage(Ab, nbA, 1, t + 1);
        PRIO1(); MQ32(afA, bfA); PRIO0();
        // P2: MFMA slice1 | read slice2 | stage B(t+2)
        ldAs(afA, bA, 2);  ldBs(bfA, bcur, 2);
        stage(Bb, 65536 + bst, 0, t + 2);  stage(Bb, 65536 + bst, 1, t + 2);
        PRIO1(); MQ32(afB, bfB); PRIO0();
        // P3: MFMA slice2 | read slice3 | vm(4): drain B(t+1)+A(t+1), keep B(t+2) | lgkm0 | BAR
        ldAs(afB, bA, 3);  ldBs(bfB, bcur, 3);
        PRIO1(); MQ32(afA, bfA); PRIO0();
        WAIT_VM(4);
        WAIT_LGKM0();
        PH_BAR();
        SCHED_FENCE();
        // P4: MFMA slice3 | read slice0 of tile t+1 (bufs just drained+barrier'd)
        ldAs(afA, nbA, 0);  ldBs(bfA, bnx, 0);
        PRIO1(); MQ32(afB, bfB); PRIO0();

        bcur = bnx;
    }

    // ---- peeled t = nt-2: stage only A(nt-1); full drain at P3 ----
    {
        const int t = nt - 2;
        const int bA  = (t & 1) << 15;
        const int nbA = (~t & 1) << 15;
        int bnx = bcur + 32768; if (bnx >= 98304) bnx -= 98304;

        ldAs(afB, bA, 1);  ldBs(bfB, bcur, 1);
        stage(Ab, nbA, 0, t + 1);  stage(Ab, nbA, 1, t + 1);
        PRIO1(); MQ32(afA, bfA); PRIO0();
        ldAs(afA, bA, 2);  ldBs(bfA, bcur, 2);
        PRIO1(); MQ32(afB, bfB); PRIO0();
        ldAs(afB, bA, 3);  ldBs(bfB, bcur, 3);
        PRIO1(); MQ32(afA, bfA); PRIO0();
        WAIT_VM(0);
        WAIT_LGKM0();
        PH_BAR();
        SCHED_FENCE();
        ldAs(afA, nbA, 0);  ldBs(bfA, bnx, 0);
        PRIO1(); MQ32(afB, bfB); PRIO0();
        bcur = bnx;
    }
    // ---- peeled t = nt-1: no staging, no barrier ----
    {
        const int bA = ((nt - 1) & 1) << 15;
        ldAs(afB, bA, 1);  ldBs(bfB, bcur, 1);
        PRIO1(); MQ32(afA, bfA); PRIO0();
        ldAs(afA, bA, 2);  ldBs(bfA, bcur, 2);
        PRIO1(); MQ32(afB, bfB); PRIO0();
        ldAs(afB, bA, 3);  ldBs(bfB, bcur, 3);
        PRIO1(); MQ32(afA, bfA); PRIO0();
        PRIO1(); MQ32(afB, bfB); PRIO0();
    }
#undef MQ32

    // ------------- epilogue: 32x32 C layout (col=l31, row=(reg&3)+8*(reg>>2)+4*hi5) -------------
    const float is = *is_p, os = *os_p;
    const float zp = (float)(*zp_p);
    const int colb = (bcol << 8) + (wc << 6) + l31;
    float sc[2]; int bv[2];
#pragma unroll
    for (int n = 0; n < 2; ++n) {
        sc[n] = is * wscale[colb + (n << 5)] / os;
        bv[n] = bias[colb + (n << 5)];
    }
#pragma unroll
    for (int mf = 0; mf < 4; ++mf) {
        const int rowbase = (brow << 8) + (wr << 7) + (mf << 5) + (hi5 << 2);
#pragma unroll
        for (int rg = 0; rg < 4; ++rg) {
#pragma unroll
            for (int j = 0; j < 4; ++j) {
                const int row = rowbase + (rg << 3) + j;
                int* op = out + (size_t)row * Ncols + colb;
#pragma unroll
                for (int n = 0; n < 2; ++n) {
                    float f = (float)(acc[mf][n][(rg << 2) + j] + bv[n]) * sc[n] + zp;
                    f = rintf(f);
                    f = fminf(fmaxf(f, -128.f), 127.f);
                    op[n << 5] = (int)f;
                }
            }
        }
    }
}

// ---------------- fallback 128^2 2-barrier kernel (known-correct) ----------------
template <bool PACKED>
__global__ __launch_bounds__(256) void gemm_q8(
    const void* __restrict__ Ain, const void* __restrict__ Bin,
    const int* __restrict__ bias, const float* __restrict__ wscale,
    const float* __restrict__ is_p, const float* __restrict__ os_p,
    const int* __restrict__ zp_p,
    int* __restrict__ out, int Nrows, int K, int Ncols)
{
    __shared__ char Al[128 * 64];
    __shared__ char Bl[128 * 64];

    const int tid  = threadIdx.x;
    const int wid  = tid >> 6;
    const int lane = tid & 63;

    const int nbc = Ncols / 128;
    int swz = blockIdx.x;
    if ((gridDim.x & 7) == 0) {
        const int cpx = gridDim.x >> 3;
        swz = (blockIdx.x & 7) * cpx + (blockIdx.x >> 3);
    }
    const int brow = swz / nbc;
    const int bcol = swz % nbc;
    const int wr = wid >> 1, wc = wid & 1;

    v4i acc[4][4];
#pragma unroll
    for (int m = 0; m < 4; ++m)
#pragma unroll
        for (int n = 0; n < 4; ++n)
            acc[m][n] = (v4i){0, 0, 0, 0};

    const char* Ag = nullptr;
    const char* Bg = nullptr;
    if (PACKED) {
        Ag = (const char*)Ain + (size_t)(brow * 128 + wid * 32 + (lane >> 2)) * K + (lane & 3) * 16;
        Bg = (const char*)Bin + (size_t)(bcol * 128 + wid * 32 + (lane >> 2)) * K + (lane & 3) * 16;
    }
    char* aldst = Al + wid * 2048;
    char* bldst = Bl + wid * 2048;

    const int lo16 = lane & 15, hi = lane >> 4;
    const int aoff0 = (wr * 64 + lo16) * 64 + hi * 16;
    const int boff0 = (wc * 64 + lo16) * 64 + hi * 16;

    for (int k0 = 0; k0 < K; k0 += 64) {
        if (PACKED) {
            GLOAD16(Ag + k0,          aldst);
            GLOAD16(Ag + 16 * K + k0, aldst + 1024);
            GLOAD16(Bg + k0,          bldst);
            GLOAD16(Bg + 16 * K + k0, bldst + 1024);
        } else {
            const int row = tid >> 1, half = tid & 1;
            const int* sA = (const int*)Ain + (size_t)(brow * 128 + row) * K + k0 + half * 32;
            const int* sB = (const int*)Bin + (size_t)(bcol * 128 + row) * K + k0 + half * 32;
            int pa[8], pb[8];
#pragma unroll
            for (int j = 0; j < 8; ++j) {
                v4i va = reinterpret_cast<const v4i*>(sA)[j];
                v4i vb = reinterpret_cast<const v4i*>(sB)[j];
                pa[j] = pack4(va.x, va.y, va.z, va.w);
                pb[j] = pack4(vb.x, vb.y, vb.z, vb.w);
            }
            v4i* da = (v4i*)&Al[row * 64 + half * 32];
            da[0] = (v4i){pa[0], pa[1], pa[2], pa[3]};
            da[1] = (v4i){pa[4], pa[5], pa[6], pa[7]};
            v4i* db = (v4i*)&Bl[row * 64 + half * 32];
            db[0] = (v4i){pb[0], pb[1], pb[2], pb[3]};
            db[1] = (v4i){pb[4], pb[5], pb[6], pb[7]};
        }
        __syncthreads();

        v4i afr[4], bfr[4];
#pragma unroll
        for (int m = 0; m < 4; ++m)
            afr[m] = *(const v4i*)&Al[aoff0 + m * 16 * 64];
#pragma unroll
        for (int n = 0; n < 4; ++n)
            bfr[n] = *(const v4i*)&Bl[boff0 + n * 16 * 64];
#pragma unroll
        for (int m = 0; m < 4; ++m)
#pragma unroll
            for (int n = 0; n < 4; ++n)
                acc[m][n] = __builtin_amdgcn_mfma_i32_16x16x64_i8(afr[m], bfr[n], acc[m][n], 0, 0, 0);

        __syncthreads();
    }

    const float is = *is_p;
    const float os = *os_p;
    const float zp = (float)(*zp_p);
#pragma unroll
    for (int n = 0; n < 4; ++n) {
        const int col = bcol * 128 + wc * 64 + n * 16 + lo16;
        const float sc = is * wscale[col] / os;
        const int   bv = bias[col];
#pragma unroll
        for (int m = 0; m < 4; ++m) {
            const int row0 = brow * 128 + wr * 64 + m * 16 + hi * 4;
#pragma unroll
            for (int j = 0; j < 4; ++j) {
                float f = (float)(acc[m][n][j] + bv) * sc + zp;
                f = rintf(f);
                f = fminf(fmaxf(f, -128.f), 127.f);
                out[(size_t)(row0 + j) * Ncols + col] = (int)f;
            }
        }
    }
}

extern "C" void kernel_launch(void* const* d_in, const int* in_sizes, int n_in,
                              void* d_out, int out_size, void* d_ws, size_t ws_size,
                              hipStream_t stream) {
    const int*   x32    = (const int*)d_in[0];
    const int*   w32    = (const int*)d_in[1];
    const int*   bias   = (const int*)d_in[2];
    const float* wscale = (const float*)d_in[3];
    const float* isp    = (const float*)d_in[4];
    const float* osp    = (const float*)d_in[5];
    const int*   zpp    = (const int*)d_in[6];
    int* out = (int*)d_out;

    const int OUT = in_sizes[2];            // 4096
    const int K   = in_sizes[1] / OUT;      // 4096
    const int Nr  = in_sizes[0] / K;        // 8192

    const size_t need = (size_t)Nr * K + (size_t)OUT * K;

    if (ws_size >= need) {
        char* xpk = (char*)d_ws;
        char* wpk = xpk + (size_t)Nr * K;
        const int nx16 = (Nr * K) / 16;
        const int nw16 = (OUT * K) / 16;
        pack2_kernel<<<(nx16 + nw16 + 255) / 256, 256, 0, stream>>>(
            x32, (v4i*)xpk, nx16, w32, (v4i*)wpk, nw16);
        if ((Nr & 255) == 0 && (OUT & 255) == 0 && (K & 127) == 0 && (K >> 7) >= 3) {
            const int grid8 = (Nr / 256) * (OUT / 256);
            gemm_q8_mp<<<grid8, 512, 0, stream>>>(xpk, wpk, bias, wscale, isp, osp, zpp,
                                                  out, K, OUT);
        } else {
            const int grid = (Nr / 128) * (OUT / 128);
            gemm_q8<true><<<grid, 256, 0, stream>>>(xpk, wpk, bias, wscale, isp, osp, zpp,
                                                    out, Nr, K, OUT);
        }
    } else {
        const int grid = (Nr / 128) * (OUT / 128);
        gemm_q8<false><<<grid, 256, 0, stream>>>(x32, w32, bias, wscale, isp, osp, zpp,
                                                 out, Nr, K, OUT);
    }
}

// Round 14
// 169.684 us; speedup vs baseline: 1.1193x; 1.1193x over previous
//
#include <hip/hip_runtime.h>
#include <stdint.h>
#include <stddef.h>

typedef int v4i __attribute__((ext_vector_type(4)));

#define GLOAD16(gp, lp) __builtin_amdgcn_global_load_lds( \
    (const __attribute__((address_space(1))) void*)(gp),  \
    (__attribute__((address_space(3))) void*)(lp), 16, 0, 0)

#define PH_BAR()     __builtin_amdgcn_s_barrier()
#define WAIT_VM(n)   asm volatile("s_waitcnt vmcnt(" #n ")" ::: "memory")
#define WAIT_LGKM0() asm volatile("s_waitcnt lgkmcnt(0)" ::: "memory")
#define SCHED_FENCE() __builtin_amdgcn_sched_barrier(0)
#define PRIO1() __builtin_amdgcn_s_setprio(1)
#define PRIO0() __builtin_amdgcn_s_setprio(0)

static __device__ __forceinline__ int pack4(int a, int b, int c, int d) {
    return (a & 255) | ((b & 255) << 8) | ((c & 255) << 16) | (d << 24);
}

// ---------------- pack: int32 (values in [-128,127]) -> int8, both arrays ----------------
__global__ __launch_bounds__(256) void pack2_kernel(const int* __restrict__ srcA, v4i* __restrict__ dstA, int nA,
                                                    const int* __restrict__ srcB, v4i* __restrict__ dstB, int nB) {
    int i = blockIdx.x * blockDim.x + threadIdx.x;
    const int* src; v4i* dst;
    if (i < nA) { src = srcA; dst = dstA; }
    else { i -= nA; if (i >= nB) return; src = srcB; dst = dstB; }
    const v4i* s = reinterpret_cast<const v4i*>(src) + (size_t)i * 4;
    v4i v0 = s[0], v1 = s[1], v2 = s[2], v3 = s[3];
    v4i r;
    r.x = pack4(v0.x, v0.y, v0.z, v0.w);
    r.y = pack4(v1.x, v1.y, v1.z, v1.w);
    r.z = pack4(v2.x, v2.y, v2.z, v2.w);
    r.w = pack4(v3.x, v3.y, v3.z, v3.w);
    dst[i] = r;
}

// ====== 256x256 i8 GEMM (ROUND-10 REVERT): 16x16x64, m-pair phases, 1 barrier/K-tile ======
// Best measured variant (GEMM 121us, MfmaUtil 51.5%, conflicts 0). 8 waves = 2Mx4N,
// per-wave out 128x64 = acc[8][4] (128 AGPR); af ping-pong 32 + bf 32 VGPR -> 244 regs.
// A 2x32KB @0, B 3x32KB @65536 (160KB LDS, 1 block/CU). Stage A(t+1)@P1, B(t+2)@P2;
// P3-end WAIT_VM(4) drains [B(t+1),A(t+1)] and leaves B(t+2) in flight across the
// barrier (T4: never vmcnt(0) in-loop). One barrier per K-tile; waves skew between
// barriers so MFMA bursts cover other waves' LDS read bursts (setprio arbitrates).
// 32x32 MFMA path abandoned: its 32-row frag-read pattern bank-conflicts (r12 PMC:
// 1.26e7 = ~20us) regardless of per-row XOR choice; 16-row pattern measures 0.
__global__ __launch_bounds__(512, 1) void gemm_q8_mp(
    const char* __restrict__ Apk, const char* __restrict__ Bpk,
    const int* __restrict__ bias, const float* __restrict__ wscale,
    const float* __restrict__ is_p, const float* __restrict__ os_p,
    const int* __restrict__ zp_p,
    int* __restrict__ out, int K, int Ncols)
{
    __shared__ char lds[163840];

    const int tid  = threadIdx.x;
    const int wid  = tid >> 6;
    const int lane = tid & 63;
    const int l7 = lane & 7, l3 = lane >> 3;
    const int lo16 = lane & 15, hi = lane >> 4;

    // bijective XCD-aware swizzle (m204)
    int swz;
    {
        const int nwg = gridDim.x;
        const int q = nwg >> 3, r = nwg & 7;
        const int xcd = blockIdx.x & 7;
        const int base = (xcd < r) ? xcd * (q + 1) : r * (q + 1) + (xcd - r) * q;
        swz = base + (blockIdx.x >> 3);
    }
    const int nbc  = Ncols >> 8;
    const int brow = swz / nbc, bcol = swz % nbc;

    const int wr = wid >> 2, wc = wid & 3;   // 2M x 4N waves, 128x64 out each

    const char* Ab = Apk + (size_t)(brow * 256 + wid * 8 + l3) * K + ((l7 ^ l3) << 4);
    const char* Bb = Bpk + (size_t)(bcol * 256 + wid * 8 + l3) * K + ((l7 ^ l3) << 4);

    // ds_read: row*128 + slot*16, slot = chunk ^ (row&7); row&7 == l7 for all frag reads
    const int colsw0 = (hi ^ l7) << 4;
    const int colsw1 = colsw0 ^ 64;
    const int aBase = (wr << 14) + (lo16 << 7);          // + Abuf + pair<<12 + m<<11
    const int bBase = (wc << 13) + (lo16 << 7);          // + 65536 + Bbuf + n<<11

    v4i acc[8][4];
#pragma unroll
    for (int m = 0; m < 8; ++m)
#pragma unroll
        for (int n = 0; n < 4; ++n)
            acc[m][n] = (v4i){0, 0, 0, 0};

    v4i afA[2][2], afB[2][2], bf[4][2];

    auto stage = [&](const char* gb, int ldsOff, int h, int t) {
        const char* g = gb + (size_t)(h * 128) * K + ((size_t)t << 7);
        char* l = lds + (ldsOff + (h << 14) + (wid << 10));
        GLOAD16(g, l);
        GLOAD16(g + (size_t)64 * K, l + 8192);
    };
    auto ldAf = [&](v4i (&dst)[2][2], int bufo, int pair) {
#pragma unroll
        for (int m = 0; m < 2; ++m) {
            const int base = bufo + aBase + (pair << 12) + (m << 11);
            dst[m][0] = *(const v4i*)(lds + base + colsw0);
            dst[m][1] = *(const v4i*)(lds + base + colsw1);
        }
    };
    auto ldBf = [&](int bufo) {      // all 4 n; s0 group first (P1 MFMAs consume s0 first)
#pragma unroll
        for (int n = 0; n < 4; ++n)
            bf[n][0] = *(const v4i*)(lds + 65536 + bufo + bBase + (n << 11) + colsw0);
#pragma unroll
        for (int n = 0; n < 4; ++n)
            bf[n][1] = *(const v4i*)(lds + 65536 + bufo + bBase + (n << 11) + colsw1);
    };

    // s-OUTER: first 8 MFMAs need only bf[.][0]; dep distance 8 per acc chain
#define MQ(afX, p) do {                                                           \
    _Pragma("unroll") for (int s_ = 0; s_ < 2; ++s_)                              \
    _Pragma("unroll") for (int m_ = 0; m_ < 2; ++m_)                              \
    _Pragma("unroll") for (int n_ = 0; n_ < 4; ++n_)                              \
        acc[((p) << 1) + m_][n_] = __builtin_amdgcn_mfma_i32_16x16x64_i8(         \
            afX[m_][s_], bf[n_][s_], acc[((p) << 1) + m_][n_], 0, 0, 0);          \
} while (0)

    // ---- prologue: stage A0 (Abuf0), B0 (Bbuf0), B1 (Bbuf1); vm(4) leaves B1 in flight ----
    stage(Ab, 0,             0, 0);  stage(Ab, 0,             1, 0);
    stage(Bb, 65536,         0, 0);  stage(Bb, 65536,         1, 0);
    stage(Bb, 65536 + 32768, 0, 1);  stage(Bb, 65536 + 32768, 1, 1);
    WAIT_VM(4);          // A0+B0 landed; B1 (4) stays in flight
    PH_BAR();
    SCHED_FENCE();
    ldAf(afA, 0, 0);

    const int nt = K >> 7;    // K-tiles of 128 B (nt >= 3 guaranteed by dispatcher)
    int bcur = 0;             // B-buf byte offset of tile t: (t%3)*32768
    for (int t = 0; t < nt - 2; ++t) {
        const int bA  = (t & 1) << 15;
        const int nbA = (~t & 1) << 15;
        int bst = bcur + 65536; if (bst >= 98304) bst -= 98304;   // (t+2)%3 buf

        // P1: bf(t) + afB<-pair1 | stage A(t+1) | MFMA pair0
        ldBf(bcur);
        ldAf(afB, bA, 1);
        stage(Ab, nbA, 0, t + 1);  stage(Ab, nbA, 1, t + 1);
        PRIO1(); MQ(afA, 0); PRIO0();
        // P2: afA<-pair2 | stage B(t+2) two tiles ahead | MFMA pair1
        ldAf(afA, bA, 2);
        stage(Bb, 65536 + bst, 0, t + 2);  stage(Bb, 65536 + bst, 1, t + 2);
        PRIO1(); MQ(afB, 1); PRIO0();
        // P3: afB<-pair3 | MFMA pair2 | counted drain: [B(t+1),A(t+1)] out, B(t+2) stays
        ldAf(afB, bA, 3);
        PRIO1(); MQ(afA, 2); PRIO0();
        WAIT_VM(4);       // FIFO: drains B(t+1)+A(t+1); leaves B(t+2) in flight
        WAIT_LGKM0();     // this wave's reads of bufs b retired (WAR-safe re-staging)
        PH_BAR();
        SCHED_FENCE();
        // P4: afA<-pair0 of tile t+1 | MFMA pair3
        ldAf(afA, nbA, 0);
        PRIO1(); MQ(afB, 3); PRIO0();

        bcur += 32768; if (bcur >= 98304) bcur -= 98304;
    }

    // ---- peeled t = nt-2: stage only A(nt-1); full drain at P3 ----
    {
        const int t = nt - 2;
        const int bA  = (t & 1) << 15;
        const int nbA = (~t & 1) << 15;
        ldBf(bcur);
        ldAf(afB, bA, 1);
        stage(Ab, nbA, 0, t + 1);  stage(Ab, nbA, 1, t + 1);
        PRIO1(); MQ(afA, 0); PRIO0();
        ldAf(afA, bA, 2);
        PRIO1(); MQ(afB, 1); PRIO0();
        ldAf(afB, bA, 3);
        PRIO1(); MQ(afA, 2); PRIO0();
        WAIT_VM(0);       // drains B(nt-1) + A(nt-1)
        WAIT_LGKM0();
        PH_BAR();
        SCHED_FENCE();
        ldAf(afA, nbA, 0);
        PRIO1(); MQ(afB, 3); PRIO0();
        bcur += 32768; if (bcur >= 98304) bcur -= 98304;
    }
    // ---- peeled t = nt-1: no staging, no barrier ----
    {
        const int bA = ((nt - 1) & 1) << 15;
        ldBf(bcur);
        ldAf(afB, bA, 1);
        PRIO1(); MQ(afA, 0); PRIO0();
        ldAf(afA, bA, 2);
        PRIO1(); MQ(afB, 1); PRIO0();
        ldAf(afB, bA, 3);
        PRIO1(); MQ(afA, 2); PRIO0();
        PRIO1(); MQ(afB, 3); PRIO0();
    }
#undef MQ

    // ---------------- epilogue: row-major store order, scales hoisted ----------------
    const float is = *is_p, os = *os_p;
    const float zp = (float)(*zp_p);
    const int colb = (bcol << 8) + (wc << 6) + lo16;
    float sc[4]; int bv[4];
#pragma unroll
    for (int n = 0; n < 4; ++n) {
        sc[n] = is * wscale[colb + (n << 4)] / os;
        bv[n] = bias[colb + (n << 4)];
    }
#pragma unroll
    for (int m = 0; m < 8; ++m) {
#pragma unroll
        for (int j = 0; j < 4; ++j) {
            const int row = (brow << 8) + (wr << 7) + (m << 4) + (hi << 2) + j;
            int* op = out + (size_t)row * Ncols + colb;
#pragma unroll
            for (int n = 0; n < 4; ++n) {
                float f = (float)(acc[m][n][j] + bv[n]) * sc[n] + zp;
                f = rintf(f);
                f = fminf(fmaxf(f, -128.f), 127.f);
                op[n << 4] = (int)f;
            }
        }
    }
}

// ---------------- fallback 128^2 2-barrier kernel (known-correct) ----------------
template <bool PACKED>
__global__ __launch_bounds__(256) void gemm_q8(
    const void* __restrict__ Ain, const void* __restrict__ Bin,
    const int* __restrict__ bias, const float* __restrict__ wscale,
    const float* __restrict__ is_p, const float* __restrict__ os_p,
    const int* __restrict__ zp_p,
    int* __restrict__ out, int Nrows, int K, int Ncols)
{
    __shared__ char Al[128 * 64];
    __shared__ char Bl[128 * 64];

    const int tid  = threadIdx.x;
    const int wid  = tid >> 6;
    const int lane = tid & 63;

    const int nbc = Ncols / 128;
    int swz = blockIdx.x;
    if ((gridDim.x & 7) == 0) {
        const int cpx = gridDim.x >> 3;
        swz = (blockIdx.x & 7) * cpx + (blockIdx.x >> 3);
    }
    const int brow = swz / nbc;
    const int bcol = swz % nbc;
    const int wr = wid >> 1, wc = wid & 1;

    v4i acc[4][4];
#pragma unroll
    for (int m = 0; m < 4; ++m)
#pragma unroll
        for (int n = 0; n < 4; ++n)
            acc[m][n] = (v4i){0, 0, 0, 0};

    const char* Ag = nullptr;
    const char* Bg = nullptr;
    if (PACKED) {
        Ag = (const char*)Ain + (size_t)(brow * 128 + wid * 32 + (lane >> 2)) * K + (lane & 3) * 16;
        Bg = (const char*)Bin + (size_t)(bcol * 128 + wid * 32 + (lane >> 2)) * K + (lane & 3) * 16;
    }
    char* aldst = Al + wid * 2048;
    char* bldst = Bl + wid * 2048;

    const int lo16 = lane & 15, hi = lane >> 4;
    const int aoff0 = (wr * 64 + lo16) * 64 + hi * 16;
    const int boff0 = (wc * 64 + lo16) * 64 + hi * 16;

    for (int k0 = 0; k0 < K; k0 += 64) {
        if (PACKED) {
            GLOAD16(Ag + k0,          aldst);
            GLOAD16(Ag + 16 * K + k0, aldst + 1024);
            GLOAD16(Bg + k0,          bldst);
            GLOAD16(Bg + 16 * K + k0, bldst + 1024);
        } else {
            const int row = tid >> 1, half = tid & 1;
            const int* sA = (const int*)Ain + (size_t)(brow * 128 + row) * K + k0 + half * 32;
            const int* sB = (const int*)Bin + (size_t)(bcol * 128 + row) * K + k0 + half * 32;
            int pa[8], pb[8];
#pragma unroll
            for (int j = 0; j < 8; ++j) {
                v4i va = reinterpret_cast<const v4i*>(sA)[j];
                v4i vb = reinterpret_cast<const v4i*>(sB)[j];
                pa[j] = pack4(va.x, va.y, va.z, va.w);
                pb[j] = pack4(vb.x, vb.y, vb.z, vb.w);
            }
            v4i* da = (v4i*)&Al[row * 64 + half * 32];
            da[0] = (v4i){pa[0], pa[1], pa[2], pa[3]};
            da[1] = (v4i){pa[4], pa[5], pa[6], pa[7]};
            v4i* db = (v4i*)&Bl[row * 64 + half * 32];
            db[0] = (v4i){pb[0], pb[1], pb[2], pb[3]};
            db[1] = (v4i){pb[4], pb[5], pb[6], pb[7]};
        }
        __syncthreads();

        v4i afr[4], bfr[4];
#pragma unroll
        for (int m = 0; m < 4; ++m)
            afr[m] = *(const v4i*)&Al[aoff0 + m * 16 * 64];
#pragma unroll
        for (int n = 0; n < 4; ++n)
            bfr[n] = *(const v4i*)&Bl[boff0 + n * 16 * 64];
#pragma unroll
        for (int m = 0; m < 4; ++m)
#pragma unroll
            for (int n = 0; n < 4; ++n)
                acc[m][n] = __builtin_amdgcn_mfma_i32_16x16x64_i8(afr[m], bfr[n], acc[m][n], 0, 0, 0);

        __syncthreads();
    }

    const float is = *is_p;
    const float os = *os_p;
    const float zp = (float)(*zp_p);
#pragma unroll
    for (int n = 0; n < 4; ++n) {
        const int col = bcol * 128 + wc * 64 + n * 16 + lo16;
        const float sc = is * wscale[col] / os;
        const int   bv = bias[col];
#pragma unroll
        for (int m = 0; m < 4; ++m) {
            const int row0 = brow * 128 + wr * 64 + m * 16 + hi * 4;
#pragma unroll
            for (int j = 0; j < 4; ++j) {
                float f = (float)(acc[m][n][j] + bv) * sc + zp;
                f = rintf(f);
                f = fminf(fmaxf(f, -128.f), 127.f);
                out[(size_t)(row0 + j) * Ncols + col] = (int)f;
            }
        }
    }
}

extern "C" void kernel_launch(void* const* d_in, const int* in_sizes, int n_in,
                              void* d_out, int out_size, void* d_ws, size_t ws_size,
                              hipStream_t stream) {
    const int*   x32    = (const int*)d_in[0];
    const int*   w32    = (const int*)d_in[1];
    const int*   bias   = (const int*)d_in[2];
    const float* wscale = (const float*)d_in[3];
    const float* isp    = (const float*)d_in[4];
    const float* osp    = (const float*)d_in[5];
    const int*   zpp    = (const int*)d_in[6];
    int* out = (int*)d_out;

    const int OUT = in_sizes[2];            // 4096
    const int K   = in_sizes[1] / OUT;      // 4096
    const int Nr  = in_sizes[0] / K;        // 8192

    const size_t need = (size_t)Nr * K + (size_t)OUT * K;

    if (ws_size >= need) {
        char* xpk = (char*)d_ws;
        char* wpk = xpk + (size_t)Nr * K;
        const int nx16 = (Nr * K) / 16;
        const int nw16 = (OUT * K) / 16;
        pack2_kernel<<<(nx16 + nw16 + 255) / 256, 256, 0, stream>>>(
            x32, (v4i*)xpk, nx16, w32, (v4i*)wpk, nw16);
        if ((Nr & 255) == 0 && (OUT & 255) == 0 && (K & 127) == 0 && (K >> 7) >= 3) {
            const int grid8 = (Nr / 256) * (OUT / 256);
            gemm_q8_mp<<<grid8, 512, 0, stream>>>(xpk, wpk, bias, wscale, isp, osp, zpp,
                                                  out, K, OUT);
        } else {
            const int grid = (Nr / 128) * (OUT / 128);
            gemm_q8<true><<<grid, 256, 0, stream>>>(xpk, wpk, bias, wscale, isp, osp, zpp,
                                                    out, Nr, K, OUT);
        }
    } else {
        const int grid = (Nr / 128) * (OUT / 128);
        gemm_q8<false><<<grid, 256, 0, stream>>>(x32, w32, bias, wscale, isp, osp, zpp,
                                                 out, Nr, K, OUT);
    }
}